// Round 10
// baseline (212.250 us; speedup 1.0000x reference)
//
#include <hip/hip_runtime.h>
#include <math.h>

// cSE channel self-attention, bf16-MFMA hi/lo, fused cooperative kernel with
// INLINE grid barrier (no __ockl_grid_sync call -> no ABI spills).
// x: [N=4][C=128][S=110592] f32.  out: same shape f32.
// energy = Q Q^T; attn_ij = exp(rowmin - e_ij)/sum (== reference softmax(max-e));
// out = attn @ Q.
//
// R9 evidence: fused traffic = 563 MB (x L3-resident for PV re-read) but
// cg::grid.sync() call forced scratch spills (VGPR 52, +77MB writes).
// R10: inline atomic barrier + launch_bounds(512,1). Fallback: R6 path.

static constexpr int CN = 128;
static constexpr int SN = 110592;      // 48^3
static constexpr int NB = 4;

static constexpr int GB = 64;          // K-slices per batch; grid = GB*NB = 256
static constexpr int GSL = SN / GB;    // 1728
static constexpr int GCH = GSL / 64;   // 27 chunks of 64

static constexpr int PB = 432;         // fallback-PV s-blocks per batch
static constexpr int PCH = 4;

typedef float  f32x4  __attribute__((ext_vector_type(4)));
typedef short  bf16x8 __attribute__((ext_vector_type(8)));
typedef unsigned short u16x8 __attribute__((ext_vector_type(8)));
typedef unsigned short u16x4 __attribute__((ext_vector_type(4)));

__device__ __forceinline__ unsigned int splitpack(float v) {
    unsigned int u = __float_as_uint(v);
    unsigned int h = (u + 0x7fffu + ((u >> 16) & 1u)) >> 16;
    float lf = v - __uint_as_float(h << 16);
    unsigned int ul = __float_as_uint(lf);
    unsigned int l = (ul + 0x7fffu + ((ul >> 16) & 1u)) >> 16;
    return (l << 16) | (h & 0xffffu);
}
__device__ __forceinline__ unsigned short f2bh(float v) {
    unsigned int u = __float_as_uint(v);
    return (unsigned short)((u + 0x7fffu + ((u >> 16) & 1u)) >> 16);
}
__device__ __forceinline__ bf16x8 ldsfrag(const unsigned short* base, int row, int kbyte, int pitchB) {
    const char* p = reinterpret_cast<const char*>(base) + row * pitchB + (kbyte ^ ((row & 7) << 4));
    return *reinterpret_cast<const bf16x8*>(p);
}
__device__ __forceinline__ f32x4 mm(bf16x8 a, bf16x8 b, f32x4 c) {
    return __builtin_amdgcn_mfma_f32_16x16x32_bf16(a, b, c, 0, 0, 0);
}

// Inline grid barrier: all blocks bump bar, spin until == target.
// Device-scope atomics (AGENT) for cross-XCD visibility; fully inlined.
__device__ __forceinline__ void grid_barrier(unsigned int* bar, unsigned int target) {
    __syncthreads();
    if (threadIdx.x == 0) {
        __threadfence();   // prior writes device-visible before signaling
        __hip_atomic_fetch_add(bar, 1u, __ATOMIC_ACQ_REL, __HIP_MEMORY_SCOPE_AGENT);
        while (__hip_atomic_load(bar, __ATOMIC_ACQUIRE, __HIP_MEMORY_SCOPE_AGENT) < target) {
            __builtin_amdgcn_s_sleep(8);
        }
    }
    __syncthreads();
}

// ================= fused cooperative kernel =================
__global__ __launch_bounds__(512, 1) void fused_cse(const float* __restrict__ x,
                                                    float* __restrict__ part,
                                                    unsigned short* __restrict__ att_h,
                                                    float* __restrict__ out,
                                                    unsigned int* __restrict__ bar) {
    __shared__ __align__(16) unsigned short lh[2][CN * 64];   // 32 KB (reused by PV)
    __shared__ __align__(16) unsigned short ll[2][CN * 64];   // 32 KB
    const int blk = blockIdx.x;
    const int n  = blk >> 6;               // batch
    const int bx = blk & 63;               // 1728-s slice
    const int tid = threadIdx.x;
    const int lane = tid & 63;
    const int w = tid >> 6;                // 0..7
    const int ra = lane & 15, kg = lane >> 4;

    // ---------------- phase 1: gram partial ----------------
    {
        const int wr = w >> 2, wc = w & 3;     // wave grid 2x4
        const int c  = tid >> 2;               // staging channel
        const int ks = (tid & 3) << 4;         // 16 consecutive k
        const float* gq = x + (size_t)n * CN * SN + (size_t)c * SN + bx * GSL;

        f32x4 acc[4][2];
#pragma unroll
        for (int a = 0; a < 4; ++a)
#pragma unroll
            for (int b = 0; b < 2; ++b) acc[a][b] = (f32x4){0.f, 0.f, 0.f, 0.f};

        float4 st[4];
        auto load_chunk = [&](int t) {
            const float4* p = reinterpret_cast<const float4*>(gq + t * 64 + ks);
            st[0] = p[0]; st[1] = p[1]; st[2] = p[2]; st[3] = p[3];
        };

        auto stage = [&](int buf) {
            u16x8 ha, hb, la, lb;
            unsigned int p;
#define CV8(hv, lv, i, val) { p = splitpack(val); hv[i] = (unsigned short)(p & 0xffffu); lv[i] = (unsigned short)(p >> 16); }
            CV8(ha, la, 0, st[0].x) CV8(ha, la, 1, st[0].y) CV8(ha, la, 2, st[0].z) CV8(ha, la, 3, st[0].w)
            CV8(ha, la, 4, st[1].x) CV8(ha, la, 5, st[1].y) CV8(ha, la, 6, st[1].z) CV8(ha, la, 7, st[1].w)
            CV8(hb, lb, 0, st[2].x) CV8(hb, lb, 1, st[2].y) CV8(hb, lb, 2, st[2].z) CV8(hb, lb, 3, st[2].w)
            CV8(hb, lb, 4, st[3].x) CV8(hb, lb, 5, st[3].y) CV8(hb, lb, 6, st[3].z) CV8(hb, lb, 7, st[3].w)
#undef CV8
            char* ph = reinterpret_cast<char*>(lh[buf]) + c * 128;
            char* pl = reinterpret_cast<char*>(ll[buf]) + c * 128;
            const int sw = (c & 7) << 4;
            const int k2 = ks * 2;
            *reinterpret_cast<u16x8*>(ph + (k2 ^ sw))        = ha;
            *reinterpret_cast<u16x8*>(ph + ((k2 + 16) ^ sw)) = hb;
            *reinterpret_cast<u16x8*>(pl + (k2 ^ sw))        = la;
            *reinterpret_cast<u16x8*>(pl + ((k2 + 16) ^ sw)) = lb;
        };

        auto compute = [&](int buf) {
            const unsigned short* LH = lh[buf];
            const unsigned short* LL = ll[buf];
#pragma unroll
            for (int kk = 0; kk < 2; ++kk) {
                const int kb = kk * 64 + (kg << 4);
                bf16x8 ah[4], al[4], bh[2], bl[2];
#pragma unroll
                for (int it = 0; it < 4; ++it) {
                    const int row = wr * 64 + it * 16 + ra;
                    ah[it] = ldsfrag(LH, row, kb, 128);
                    al[it] = ldsfrag(LL, row, kb, 128);
                }
#pragma unroll
                for (int jt = 0; jt < 2; ++jt) {
                    const int row = wc * 32 + jt * 16 + ra;
                    bh[jt] = ldsfrag(LH, row, kb, 128);
                    bl[jt] = ldsfrag(LL, row, kb, 128);
                }
#pragma unroll
                for (int it = 0; it < 4; ++it)
#pragma unroll
                    for (int jt = 0; jt < 2; ++jt) {
                        acc[it][jt] = mm(ah[it], bh[jt], acc[it][jt]);
                        acc[it][jt] = mm(ah[it], bl[jt], acc[it][jt]);
                        acc[it][jt] = mm(al[it], bh[jt], acc[it][jt]);
                    }
            }
        };

        load_chunk(0);
        for (int t = 0; t < GCH; ++t) {
            stage(t & 1);
            if (t < GCH - 1) load_chunk(t + 1);
            __syncthreads();
            compute(t & 1);
        }

        const int q4 = kg << 2;
        float* P = part + (size_t)(n * GB + bx) * (CN * CN);
#pragma unroll
        for (int it = 0; it < 4; ++it)
#pragma unroll
            for (int jt = 0; jt < 2; ++jt)
#pragma unroll
                for (int q = 0; q < 4; ++q)
                    __builtin_nontemporal_store(acc[it][jt][q],
                        &P[(wr * 64 + it * 16 + q4 + q) * CN + wc * 32 + jt * 16 + ra]);
    }

    grid_barrier(bar, GB * NB);

    // ---------------- phase 2: reduce + softmin (waves 0,1) ----------------
    if (w < 2) {
        const int r = blk * 2 + w;             // 0..511
        const int fn = r >> 7, fi = r & 127;
        const float* p = part + (size_t)fn * GB * (CN * CN) + fi * CN;
        float e0 = 0.f, e1 = 0.f;
#pragma unroll 8
        for (int k = 0; k < GB; ++k) {
            e0 += __builtin_nontemporal_load(&p[(size_t)k * (CN * CN) + lane]);
            e1 += __builtin_nontemporal_load(&p[(size_t)k * (CN * CN) + lane + 64]);
        }
        float m = fminf(e0, e1);
#pragma unroll
        for (int off = 32; off > 0; off >>= 1) m = fminf(m, __shfl_xor(m, off));
        const float p0 = expf(m - e0);
        const float p1 = expf(m - e1);
        float s = p0 + p1;
#pragma unroll
        for (int off = 32; off > 0; off >>= 1) s += __shfl_xor(s, off);
        const float inv = 1.f / s;
        const size_t o = ((size_t)fn * CN + fi) * CN;
        att_h[o + lane]      = f2bh(p0 * inv);
        att_h[o + lane + 64] = f2bh(p1 * inv);
    }

    grid_barrier(bar + 16, GB * NB);   // separate cache line

    // ---------------- phase 3: PV over this block's 1728-s slice ----------------
    {
        bf16x8 a_h[4];   // A-fragments loaded ONCE per block (27 chunks)
        {
            const size_t rowoff = ((size_t)n * CN + w * 16 + ra) * CN + kg * 8;
            const unsigned short* Ah = att_h + rowoff;
#pragma unroll
            for (int kk = 0; kk < 4; ++kk)
                a_h[kk] = *reinterpret_cast<const bf16x8*>(Ah + kk * 32);
        }

        const int j0 = (tid >> 4) * 4;          // 0..124
        const int s0 = (tid & 15) * 4;          // 0..60
        const float* gx = x + (size_t)n * CN * SN;
        const int sbase = bx * GSL;

        f32x4 st[4];
        auto pv_load = [&](int sb) {
#pragma unroll
            for (int r = 0; r < 4; ++r)
                st[r] = *reinterpret_cast<const f32x4*>(gx + (size_t)(j0 + r) * SN + sb + s0);
        };

        auto pv_stage = [&](int buf) {
            char* base = reinterpret_cast<char*>(lh[buf]);
#pragma unroll
            for (int r = 0; r < 4; ++r) {
                u16x4 hv;
                hv[0] = f2bh(st[0][r]);
                hv[1] = f2bh(st[1][r]);
                hv[2] = f2bh(st[2][r]);
                hv[3] = f2bh(st[3][r]);
                const int s = s0 + r;
                const int off = s * 256 + ((j0 * 2) ^ ((s & 7) << 4));
                *reinterpret_cast<u16x4*>(base + off) = hv;
            }
        };

        auto pv_compute = [&](int buf, int sb) {
            const unsigned short* Q = lh[buf];
#pragma unroll
            for (int stile = 0; stile < 4; ++stile) {
                f32x4 acc = (f32x4){0.f, 0.f, 0.f, 0.f};
                const int srow = stile * 16 + ra;
#pragma unroll
                for (int kk = 0; kk < 4; ++kk) {
                    const int kb = kk * 64 + (kg << 4);
                    bf16x8 bh = ldsfrag(Q, srow, kb, 256);
                    acc = mm(a_h[kk], bh, acc);
                }
                float* o = out + ((size_t)n * CN + w * 16 + (kg << 2)) * SN + sb + stile * 16 + ra;
#pragma unroll
                for (int q = 0; q < 4; ++q)
                    __builtin_nontemporal_store(acc[q], o + (size_t)q * SN);
            }
        };

        pv_load(sbase);
        for (int t = 0; t < GCH; ++t) {
            pv_stage(t & 1);
            if (t < GCH - 1) pv_load(sbase + (t + 1) * 64);
            __syncthreads();
            pv_compute(t & 1, sbase + t * 64);
        }
    }
}

// ================= fallback 3-kernel path (round-6) =================
template <bool ATOMIC>
__global__ __launch_bounds__(512, 2) void gram_mfma(const float* __restrict__ x,
                                                    float* __restrict__ dst) {
    __shared__ __align__(16) unsigned short lh[2][CN * 64];
    __shared__ __align__(16) unsigned short ll[2][CN * 64];
    const int bx = blockIdx.x, n = blockIdx.y;
    const int tid = threadIdx.x;
    const int lane = tid & 63;
    const int w = tid >> 6;
    const int wr = w >> 2, wc = w & 3;
    const int ra = lane & 15, kg = lane >> 4;
    const int c  = tid >> 2;
    const int ks = (tid & 3) << 4;
    const float* gq = x + (size_t)n * CN * SN + (size_t)c * SN + bx * GSL;

    f32x4 acc[4][2];
#pragma unroll
    for (int a = 0; a < 4; ++a)
#pragma unroll
        for (int b = 0; b < 2; ++b) acc[a][b] = (f32x4){0.f, 0.f, 0.f, 0.f};

    float4 st[4];
    auto load_chunk = [&](int t) {
        const float4* p = reinterpret_cast<const float4*>(gq + t * 64 + ks);
        st[0] = p[0]; st[1] = p[1]; st[2] = p[2]; st[3] = p[3];
    };
    auto stage = [&](int buf) {
        u16x8 ha, hb, la, lb;
        unsigned int p;
#define CV8(hv, lv, i, val) { p = splitpack(val); hv[i] = (unsigned short)(p & 0xffffu); lv[i] = (unsigned short)(p >> 16); }
        CV8(ha, la, 0, st[0].x) CV8(ha, la, 1, st[0].y) CV8(ha, la, 2, st[0].z) CV8(ha, la, 3, st[0].w)
        CV8(ha, la, 4, st[1].x) CV8(ha, la, 5, st[1].y) CV8(ha, la, 6, st[1].z) CV8(ha, la, 7, st[1].w)
        CV8(hb, lb, 0, st[2].x) CV8(hb, lb, 1, st[2].y) CV8(hb, lb, 2, st[2].z) CV8(hb, lb, 3, st[2].w)
        CV8(hb, lb, 4, st[3].x) CV8(hb, lb, 5, st[3].y) CV8(hb, lb, 6, st[3].z) CV8(hb, lb, 7, st[3].w)
#undef CV8
        char* ph = reinterpret_cast<char*>(lh[buf]) + c * 128;
        char* pl = reinterpret_cast<char*>(ll[buf]) + c * 128;
        const int sw = (c & 7) << 4;
        const int k2 = ks * 2;
        *reinterpret_cast<u16x8*>(ph + (k2 ^ sw))        = ha;
        *reinterpret_cast<u16x8*>(ph + ((k2 + 16) ^ sw)) = hb;
        *reinterpret_cast<u16x8*>(pl + (k2 ^ sw))        = la;
        *reinterpret_cast<u16x8*>(pl + ((k2 + 16) ^ sw)) = lb;
    };
    auto compute = [&](int buf) {
        const unsigned short* LH = lh[buf];
        const unsigned short* LL = ll[buf];
#pragma unroll
        for (int kk = 0; kk < 2; ++kk) {
            const int kb = kk * 64 + (kg << 4);
            bf16x8 ah[4], al[4], bh[2], bl[2];
#pragma unroll
            for (int it = 0; it < 4; ++it) {
                const int row = wr * 64 + it * 16 + ra;
                ah[it] = ldsfrag(LH, row, kb, 128);
                al[it] = ldsfrag(LL, row, kb, 128);
            }
#pragma unroll
            for (int jt = 0; jt < 2; ++jt) {
                const int row = wc * 32 + jt * 16 + ra;
                bh[jt] = ldsfrag(LH, row, kb, 128);
                bl[jt] = ldsfrag(LL, row, kb, 128);
            }
#pragma unroll
            for (int it = 0; it < 4; ++it)
#pragma unroll
                for (int jt = 0; jt < 2; ++jt) {
                    acc[it][jt] = mm(ah[it], bh[jt], acc[it][jt]);
                    acc[it][jt] = mm(ah[it], bl[jt], acc[it][jt]);
                    acc[it][jt] = mm(al[it], bh[jt], acc[it][jt]);
                }
        }
    };

    load_chunk(0);
    for (int t = 0; t < GCH; ++t) {
        stage(t & 1);
        if (t < GCH - 1) load_chunk(t + 1);
        __syncthreads();
        compute(t & 1);
    }

    const int q4 = kg << 2;
    if (!ATOMIC) {
        float* P = dst + (size_t)(n * GB + bx) * (CN * CN);
#pragma unroll
        for (int it = 0; it < 4; ++it)
#pragma unroll
            for (int jt = 0; jt < 2; ++jt)
#pragma unroll
                for (int q = 0; q < 4; ++q)
                    __builtin_nontemporal_store(acc[it][jt][q],
                        &P[(wr * 64 + it * 16 + q4 + q) * CN + wc * 32 + jt * 16 + ra]);
    } else {
        float* E = dst + (size_t)n * CN * CN;
#pragma unroll
        for (int it = 0; it < 4; ++it)
#pragma unroll
            for (int jt = 0; jt < 2; ++jt)
#pragma unroll
                for (int q = 0; q < 4; ++q)
                    atomicAdd(&E[(wr * 64 + it * 16 + q4 + q) * CN + wc * 32 + jt * 16 + ra], acc[it][jt][q]);
    }
}

template <bool REDUCE>
__global__ void finish_kernel(const float* __restrict__ src,
                              unsigned short* __restrict__ att_h) {
    const int i = blockIdx.x, n = blockIdx.y, l = threadIdx.x;
    float e0, e1;
    if (REDUCE) {
        const float* p = src + (size_t)n * GB * (CN * CN) + i * CN;
        e0 = 0.f; e1 = 0.f;
#pragma unroll 8
        for (int k = 0; k < GB; ++k) {
            e0 += __builtin_nontemporal_load(&p[(size_t)k * (CN * CN) + l]);
            e1 += __builtin_nontemporal_load(&p[(size_t)k * (CN * CN) + l + 64]);
        }
    } else {
        const float* E = src + ((size_t)n * CN + i) * CN;
        e0 = E[l]; e1 = E[l + 64];
    }
    float m = fminf(e0, e1);
#pragma unroll
    for (int off = 32; off > 0; off >>= 1) m = fminf(m, __shfl_xor(m, off));
    const float p0 = expf(m - e0);
    const float p1 = expf(m - e1);
    float s = p0 + p1;
#pragma unroll
    for (int off = 32; off > 0; off >>= 1) s += __shfl_xor(s, off);
    const float inv = 1.f / s;
    const size_t o = ((size_t)n * CN + i) * CN;
    att_h[o + l]      = f2bh(p0 * inv);
    att_h[o + l + 64] = f2bh(p1 * inv);
}

__global__ __launch_bounds__(512, 4) void pv_mfma(const float* __restrict__ x,
                                                  const unsigned short* __restrict__ att_h,
                                                  float* __restrict__ out) {
    __shared__ __align__(16) unsigned short qh[2][64 * CN];
    const int bx = blockIdx.x, n = blockIdx.y;
    const int tid = threadIdx.x;
    const int lane = tid & 63;
    const int w = tid >> 6;
    const int ra = lane & 15, kg = lane >> 4;

    bf16x8 a_h[4];
    {
        const size_t rowoff = ((size_t)n * CN + w * 16 + ra) * CN + kg * 8;
        const unsigned short* Ah = att_h + rowoff;
#pragma unroll
        for (int kk = 0; kk < 4; ++kk)
            a_h[kk] = *reinterpret_cast<const bf16x8*>(Ah + kk * 32);
    }

    const int j0 = (tid >> 4) * 4;
    const int s0 = (tid & 15) * 4;
    const float* gx = x + (size_t)n * CN * SN;
    const int sbase = bx * (PCH * 64);

    f32x4 st[4];
    auto load_chunk = [&](int sb) {
#pragma unroll
        for (int r = 0; r < 4; ++r)
            st[r] = *reinterpret_cast<const f32x4*>(gx + (size_t)(j0 + r) * SN + sb + s0);
    };
    auto stage = [&](int buf) {
        char* base = reinterpret_cast<char*>(qh[buf]);
#pragma unroll
        for (int r = 0; r < 4; ++r) {
            u16x4 hv;
            hv[0] = f2bh(st[0][r]);
            hv[1] = f2bh(st[1][r]);
            hv[2] = f2bh(st[2][r]);
            hv[3] = f2bh(st[3][r]);
            const int s = s0 + r;
            const int off = s * 256 + ((j0 * 2) ^ ((s & 7) << 4));
            *reinterpret_cast<u16x4*>(base + off) = hv;
        }
    };
    auto compute = [&](int buf, int sb) {
        const unsigned short* Q = qh[buf];
#pragma unroll
        for (int stile = 0; stile < 4; ++stile) {
            f32x4 acc = (f32x4){0.f, 0.f, 0.f, 0.f};
            const int srow = stile * 16 + ra;
#pragma unroll
            for (int kk = 0; kk < 4; ++kk) {
                const int kb = kk * 64 + (kg << 4);
                bf16x8 bh = ldsfrag(Q, srow, kb, 256);
                acc = mm(a_h[kk], bh, acc);
            }
            float* o = out + ((size_t)n * CN + w * 16 + (kg << 2)) * SN + sb + stile * 16 + ra;
#pragma unroll
            for (int q = 0; q < 4; ++q)
                __builtin_nontemporal_store(acc[q], o + (size_t)q * SN);
        }
    };

    load_chunk(sbase);
    for (int t = 0; t < PCH; ++t) {
        stage(t & 1);
        if (t < PCH - 1) load_chunk(sbase + (t + 1) * 64);
        __syncthreads();
        compute(t & 1, sbase + t * 64);
    }
}

extern "C" void kernel_launch(void* const* d_in, const int* in_sizes, int n_in,
                              void* d_out, int out_size, void* d_ws, size_t ws_size,
                              hipStream_t stream) {
    (void)in_sizes; (void)n_in; (void)out_size;
    const float* x = (const float*)d_in[0];
    float* out = (float*)d_out;

    // ws: [energy 256KB][att_h 128KB][partials 16.8MB][barrier 128B]
    float* energy = (float*)d_ws;
    unsigned short* att_h = (unsigned short*)(energy + (size_t)NB * CN * CN);
    float* part = (float*)(att_h + (size_t)NB * CN * CN);
    unsigned int* bar = (unsigned int*)(part + (size_t)NB * GB * CN * CN);
    const size_t need =
        (size_t)NB * CN * CN * sizeof(float) +
        (size_t)NB * CN * CN * sizeof(unsigned short) +
        (size_t)NB * GB * CN * CN * sizeof(float) + 128;

    if (ws_size >= need) {
        // zero barrier counters each launch (graph-safe, deterministic)
        hipMemsetAsync(bar, 0, 128, stream);
        const float* xa = x;
        float* pa = part;
        unsigned short* aa = att_h;
        float* oa = out;
        unsigned int* ba = bar;
        void* args[] = {(void*)&xa, (void*)&pa, (void*)&aa, (void*)&oa, (void*)&ba};
        hipError_t err = hipLaunchCooperativeKernel(
            (const void*)fused_cse, dim3(GB * NB), dim3(512), args, 0, stream);
        if (err == hipSuccess) return;

        // cooperative launch unavailable -> round-6 path
        gram_mfma<false><<<dim3(GB, NB), 512, 0, stream>>>(x, part);
        finish_kernel<true><<<dim3(CN, NB), 64, 0, stream>>>(part, att_h);
        pv_mfma<<<dim3(PB, NB), 512, 0, stream>>>(x, att_h, out);
    } else {
        hipMemsetAsync(energy, 0, (size_t)NB * CN * CN * sizeof(float), stream);
        gram_mfma<true><<<dim3(GB, NB), 512, 0, stream>>>(x, energy);
        finish_kernel<false><<<dim3(CN, NB), 64, 0, stream>>>(energy, att_h);
        pv_mfma<<<dim3(PB, NB), 512, 0, stream>>>(x, att_h, out);
    }
}

// Round 11
// 147.429 us; speedup vs baseline: 1.4397x; 1.4397x over previous
//
#include <hip/hip_runtime.h>
#include <math.h>

// cSE channel self-attention, bf16-MFMA hi/lo, double-buffered 3-kernel path.
// x: [N=4][C=128][S=110592] f32.  out: same shape f32.
// energy = Q Q^T; attn_ij = exp(rowmin - e_ij)/sum (== reference softmax(max-e));
// out = attn @ Q.
//
// R11: fused/cooperative abandoned (R9/R10: intrinsic spill+latency pathology,
// +74us). PV + finish identical to R6 (138.4us best). Gram rewritten with
// 64x64 wave tiles to cut LDS fragment-read amplification 6x -> 4x per byte
// (gram was LDS-pipe-bound: 224KB LDS traffic vs ~3200cy HBM budget/chunk):
// 256-thr blocks, 4 waves, 2x2 tile grid, GB=128 (512 blocks = 2/CU), K=32.

static constexpr int CN = 128;
static constexpr int SN = 110592;      // 48^3
static constexpr int NB = 4;

static constexpr int GB = 128;         // gram K-slices per batch (512 blocks = 2/CU)
static constexpr int GSL = SN / GB;    // 864
static constexpr int GCH = GSL / 32;   // 27 chunks of K=32

static constexpr int PB = 432;         // pv s-blocks per batch (256 s each)
static constexpr int PCH = 4;          // chunks of 64 s per block

typedef float  f32x4  __attribute__((ext_vector_type(4)));
typedef short  bf16x8 __attribute__((ext_vector_type(8)));
typedef unsigned short u16x8 __attribute__((ext_vector_type(8)));
typedef unsigned short u16x4 __attribute__((ext_vector_type(4)));

// f32 -> (hi bf16, lo bf16) round-to-nearest-even, packed lo<<16|hi
__device__ __forceinline__ unsigned int splitpack(float v) {
    unsigned int u = __float_as_uint(v);
    unsigned int h = (u + 0x7fffu + ((u >> 16) & 1u)) >> 16;
    float lf = v - __uint_as_float(h << 16);
    unsigned int ul = __float_as_uint(lf);
    unsigned int l = (ul + 0x7fffu + ((ul >> 16) & 1u)) >> 16;
    return (l << 16) | (h & 0xffffu);
}
__device__ __forceinline__ unsigned short f2bh(float v) {
    unsigned int u = __float_as_uint(v);
    return (unsigned short)((u + 0x7fffu + ((u >> 16) & 1u)) >> 16);
}

// swizzled LDS fragment reads
__device__ __forceinline__ bf16x8 ldsfrag128(const unsigned short* base, int row, int kbyte) {
    // pitch 128B, swizzle (row&7)<<4
    const char* p = reinterpret_cast<const char*>(base) + row * 128 + (kbyte ^ ((row & 7) << 4));
    return *reinterpret_cast<const bf16x8*>(p);
}
__device__ __forceinline__ bf16x8 ldsfrag64(const unsigned short* base, int row, int kbyte) {
    // pitch 64B, swizzle (row&3)<<4 (stays within 64B row)
    const char* p = reinterpret_cast<const char*>(base) + row * 64 + (kbyte ^ ((row & 3) << 4));
    return *reinterpret_cast<const bf16x8*>(p);
}
__device__ __forceinline__ bf16x8 ldsfrag256(const unsigned short* base, int row, int kbyte) {
    // pitch 256B, swizzle (row&7)<<4
    const char* p = reinterpret_cast<const char*>(base) + row * 256 + (kbyte ^ ((row & 7) << 4));
    return *reinterpret_cast<const bf16x8*>(p);
}
__device__ __forceinline__ f32x4 mm(bf16x8 a, bf16x8 b, f32x4 c) {
    return __builtin_amdgcn_mfma_f32_16x16x32_bf16(a, b, c, 0, 0, 0);
}

// ---------------- K1: Gram via MFMA, hi/lo split, 64x64 wave tiles ----------------
// grid (GB, NB), block 256 (4 waves, 2x2 tile grid). K-slice 864 = 27 chunks of 32.
// LDS: 2 x ([128 c][32 k] bf16 hi + lo), pitch 64B, (row&3) XOR swizzle. 32 KB.
template <bool ATOMIC>
__global__ __launch_bounds__(256, 2) void gram_mfma(const float* __restrict__ x,
                                                    float* __restrict__ dst) {
    __shared__ __align__(16) unsigned short lh[2][CN * 32];   // 8 KB each buf
    __shared__ __align__(16) unsigned short ll[2][CN * 32];
    const int bx = blockIdx.x, n = blockIdx.y;
    const int tid = threadIdx.x;
    const int lane = tid & 63;
    const int w = tid >> 6;                // 0..3
    const int wr = w >> 1, wc = w & 1;     // wave grid 2x2, tile 64x64
    const int ra = lane & 15, kg = lane >> 4;

    // staging: thread -> (row c = tid>>1, 16 consecutive k = (tid&1)*16)
    const int c  = tid >> 1;               // 0..127
    const int ks = (tid & 1) << 4;         // 0 or 16 (elements)
    const float* gq = x + (size_t)n * CN * SN + (size_t)c * SN + bx * GSL;

    f32x4 acc[4][4];
#pragma unroll
    for (int a = 0; a < 4; ++a)
#pragma unroll
        for (int b = 0; b < 4; ++b) acc[a][b] = (f32x4){0.f, 0.f, 0.f, 0.f};

    float4 st[4];
    auto load_chunk = [&](int t) {
        const float4* p = reinterpret_cast<const float4*>(gq + t * 32 + ks);
        st[0] = p[0]; st[1] = p[1]; st[2] = p[2]; st[3] = p[3];
    };

    auto stage = [&](int buf) {
        u16x8 ha, hb, la, lb;
        unsigned int p;
#define CV8(hv, lv, i, val) { p = splitpack(val); hv[i] = (unsigned short)(p & 0xffffu); lv[i] = (unsigned short)(p >> 16); }
        CV8(ha, la, 0, st[0].x) CV8(ha, la, 1, st[0].y) CV8(ha, la, 2, st[0].z) CV8(ha, la, 3, st[0].w)
        CV8(ha, la, 4, st[1].x) CV8(ha, la, 5, st[1].y) CV8(ha, la, 6, st[1].z) CV8(ha, la, 7, st[1].w)
        CV8(hb, lb, 0, st[2].x) CV8(hb, lb, 1, st[2].y) CV8(hb, lb, 2, st[2].z) CV8(hb, lb, 3, st[2].w)
        CV8(hb, lb, 4, st[3].x) CV8(hb, lb, 5, st[3].y) CV8(hb, lb, 6, st[3].z) CV8(hb, lb, 7, st[3].w)
#undef CV8
        char* ph = reinterpret_cast<char*>(lh[buf]) + c * 64;
        char* pl = reinterpret_cast<char*>(ll[buf]) + c * 64;
        const int sw = (c & 3) << 4;
        const int k2 = ks * 2;             // 0 or 32 bytes
        *reinterpret_cast<u16x8*>(ph + (k2 ^ sw))        = ha;
        *reinterpret_cast<u16x8*>(ph + ((k2 + 16) ^ sw)) = hb;
        *reinterpret_cast<u16x8*>(pl + (k2 ^ sw))        = la;
        *reinterpret_cast<u16x8*>(pl + ((k2 + 16) ^ sw)) = lb;
    };

    auto compute = [&](int buf) {
        const unsigned short* LH = lh[buf];
        const unsigned short* LL = ll[buf];
        const int kb = kg << 4;            // 0..48 bytes (K=32)
        bf16x8 ah[4], al[4], bh[4], bl[4];
#pragma unroll
        for (int it = 0; it < 4; ++it) {
            const int row = wr * 64 + it * 16 + ra;
            ah[it] = ldsfrag64(LH, row, kb);
            al[it] = ldsfrag64(LL, row, kb);
        }
#pragma unroll
        for (int jt = 0; jt < 4; ++jt) {
            const int row = wc * 64 + jt * 16 + ra;
            bh[jt] = ldsfrag64(LH, row, kb);
            bl[jt] = ldsfrag64(LL, row, kb);
        }
#pragma unroll
        for (int it = 0; it < 4; ++it)
#pragma unroll
            for (int jt = 0; jt < 4; ++jt) {
                acc[it][jt] = mm(ah[it], bh[jt], acc[it][jt]);
                acc[it][jt] = mm(ah[it], bl[jt], acc[it][jt]);
                acc[it][jt] = mm(al[it], bh[jt], acc[it][jt]);
            }
    };

    load_chunk(0);
    for (int t = 0; t < GCH; ++t) {
        stage(t & 1);
        if (t < GCH - 1) load_chunk(t + 1);   // prefetch overlaps MFMA
        __syncthreads();                      // single barrier per chunk (dbuf)
        compute(t & 1);
    }

    // epilogue: C/D map row=(lane>>4)*4+q, col=lane&15
    const int q4 = kg << 2;
    if (!ATOMIC) {
        float* P = dst + (size_t)(n * GB + bx) * (CN * CN);
#pragma unroll
        for (int it = 0; it < 4; ++it)
#pragma unroll
            for (int jt = 0; jt < 4; ++jt)
#pragma unroll
                for (int q = 0; q < 4; ++q)
                    __builtin_nontemporal_store(acc[it][jt][q],
                        &P[(wr * 64 + it * 16 + q4 + q) * CN + wc * 64 + jt * 16 + ra]);
    } else {
        float* E = dst + (size_t)n * CN * CN;
#pragma unroll
        for (int it = 0; it < 4; ++it)
#pragma unroll
            for (int jt = 0; jt < 4; ++jt)
#pragma unroll
                for (int q = 0; q < 4; ++q)
                    atomicAdd(&E[(wr * 64 + it * 16 + q4 + q) * CN + wc * 64 + jt * 16 + ra], acc[it][jt][q]);
    }
}

// ---------------- K2: fused reduce + softmin -> bf16-hi attention ----------------
// grid (CN, NB), block 64 (one wave per row). Deterministic fixed-order k sum.
template <bool REDUCE>
__global__ void finish_kernel(const float* __restrict__ src,
                              unsigned short* __restrict__ att_h) {
    const int i = blockIdx.x, n = blockIdx.y, l = threadIdx.x;
    float e0, e1;
    if (REDUCE) {
        const float* p = src + (size_t)n * GB * (CN * CN) + i * CN;
        e0 = 0.f; e1 = 0.f;
#pragma unroll 8
        for (int k = 0; k < GB; ++k) {
            e0 += __builtin_nontemporal_load(&p[(size_t)k * (CN * CN) + l]);
            e1 += __builtin_nontemporal_load(&p[(size_t)k * (CN * CN) + l + 64]);
        }
    } else {
        const float* E = src + ((size_t)n * CN + i) * CN;
        e0 = E[l]; e1 = E[l + 64];
    }
    float m = fminf(e0, e1);
#pragma unroll
    for (int off = 32; off > 0; off >>= 1) m = fminf(m, __shfl_xor(m, off));
    const float p0 = expf(m - e0);
    const float p1 = expf(m - e1);
    float s = p0 + p1;
#pragma unroll
    for (int off = 32; off > 0; off >>= 1) s += __shfl_xor(s, off);
    const float inv = 1.f / s;
    const size_t o = ((size_t)n * CN + i) * CN;
    att_h[o + l]      = f2bh(p0 * inv);
    att_h[o + l + 64] = f2bh(p1 * inv);
}

// ---------------- K3: out = attn @ Q via MFMA, double-buffered (R6 exact) ----------------
// grid (PB, NB), block 512. Per block: 256 s (4 chunks of 64).
// A = attn-hi in registers. B = q-hi. x loads normal, out stores NT.
// LDS: 2 x [64 s][128 j] bf16 hi, pitch 256B, XOR-swizzled.  32 KB.
__global__ __launch_bounds__(512, 4) void pv_mfma(const float* __restrict__ x,
                                                  const unsigned short* __restrict__ att_h,
                                                  float* __restrict__ out) {
    __shared__ __align__(16) unsigned short qh[2][64 * CN];
    const int bx = blockIdx.x, n = blockIdx.y;
    const int tid = threadIdx.x;
    const int lane = tid & 63;
    const int w = tid >> 6;                 // wave -> i-tile (rows w*16..w*16+15)
    const int ra = lane & 15, kg = lane >> 4;

    // A-fragments from global (attn L2/L3-resident across blocks)
    bf16x8 a_h[4];
    {
        const size_t rowoff = ((size_t)n * CN + w * 16 + ra) * CN + kg * 8;
        const unsigned short* Ah = att_h + rowoff;
#pragma unroll
        for (int kk = 0; kk < 4; ++kk)
            a_h[kk] = *reinterpret_cast<const bf16x8*>(Ah + kk * 32);
    }

    // staging mapping: thread -> 4x4 micro-block (j0..j0+3, s0..s0+3)
    const int j0 = (tid >> 4) * 4;          // 0..124
    const int s0 = (tid & 15) * 4;          // 0..60
    const float* gx = x + (size_t)n * CN * SN;
    const int sbase = bx * (PCH * 64);

    f32x4 st[4];
    auto load_chunk = [&](int sb) {
#pragma unroll
        for (int r = 0; r < 4; ++r)
            st[r] = *reinterpret_cast<const f32x4*>(gx + (size_t)(j0 + r) * SN + sb + s0);
    };

    auto stage = [&](int buf) {
        char* base = reinterpret_cast<char*>(qh[buf]);
#pragma unroll
        for (int r = 0; r < 4; ++r) {       // r = local s offset (compile-time)
            u16x4 hv;
            hv[0] = f2bh(st[0][r]);
            hv[1] = f2bh(st[1][r]);
            hv[2] = f2bh(st[2][r]);
            hv[3] = f2bh(st[3][r]);
            const int s = s0 + r;
            const int off = s * 256 + ((j0 * 2) ^ ((s & 7) << 4));
            *reinterpret_cast<u16x4*>(base + off) = hv;
        }
    };

    auto compute = [&](int buf, int sb) {
        const unsigned short* Q = qh[buf];
#pragma unroll
        for (int stile = 0; stile < 4; ++stile) {
            f32x4 acc = (f32x4){0.f, 0.f, 0.f, 0.f};
            const int srow = stile * 16 + ra;
#pragma unroll
            for (int kk = 0; kk < 4; ++kk) {
                const int kb = kk * 64 + (kg << 4);
                bf16x8 bh = ldsfrag256(Q, srow, kb);
                acc = mm(a_h[kk], bh, acc);
            }
            float* o = out + ((size_t)n * CN + w * 16 + (kg << 2)) * SN + sb + stile * 16 + ra;
#pragma unroll
            for (int q = 0; q < 4; ++q)
                __builtin_nontemporal_store(acc[q], o + (size_t)q * SN);
        }
    };

    load_chunk(sbase);
    for (int t = 0; t < PCH; ++t) {
        stage(t & 1);
        if (t < PCH - 1) load_chunk(sbase + (t + 1) * 64);
        __syncthreads();
        compute(t & 1, sbase + t * 64);
    }
}

extern "C" void kernel_launch(void* const* d_in, const int* in_sizes, int n_in,
                              void* d_out, int out_size, void* d_ws, size_t ws_size,
                              hipStream_t stream) {
    (void)in_sizes; (void)n_in; (void)out_size;
    const float* x = (const float*)d_in[0];
    float* out = (float*)d_out;

    // ws: [energy 256KB][att_h 128KB][partials 33.6MB]
    float* energy = (float*)d_ws;
    unsigned short* att_h = (unsigned short*)(energy + (size_t)NB * CN * CN);
    float* part = (float*)(att_h + (size_t)NB * CN * CN);
    const size_t need =
        (size_t)NB * CN * CN * sizeof(float) +
        (size_t)NB * CN * CN * sizeof(unsigned short) +
        (size_t)NB * GB * CN * CN * sizeof(float);

    if (ws_size >= need) {
        gram_mfma<false><<<dim3(GB, NB), 256, 0, stream>>>(x, part);
        finish_kernel<true><<<dim3(CN, NB), 64, 0, stream>>>(part, att_h);
    } else {
        hipMemsetAsync(energy, 0, (size_t)NB * CN * CN * sizeof(float), stream);
        gram_mfma<true><<<dim3(GB, NB), 256, 0, stream>>>(x, energy);
        finish_kernel<false><<<dim3(CN, NB), 64, 0, stream>>>(energy, att_h);
    }
    pv_mfma<<<dim3(PB, NB), 512, 0, stream>>>(x, att_h, out);
}

// Round 12
// 138.649 us; speedup vs baseline: 1.5308x; 1.0633x over previous
//
#include <hip/hip_runtime.h>
#include <math.h>

// cSE channel self-attention, bf16-MFMA hi/lo, double-buffered 3-kernel path.
// x: [N=4][C=128][S=110592] f32.  out: same shape f32.
// energy = Q Q^T; attn_ij = exp(rowmin - e_ij)/sum (== reference softmax(max-e));
// out = attn @ Q.
//
// R12: R6 structure (138.4us best) with two targeted changes:
//  (1) gram: 64x64 wave tiles via 2-wave K-split (LDS frag reads -33%/chunk,
//      2700->1930cy vs 3196cy HBM budget), GB=64 so partial traffic UNCHANGED,
//      staging identical; one-time LDS acc-exchange epilogue (fixed order).
//  (2) finish: 4 waves/row (k-sum split 4x16 + LDS tree, fixed order) to fix
//      latency-bound scattered partial reads.
// PV byte-identical to R6.

static constexpr int CN = 128;
static constexpr int SN = 110592;      // 48^3
static constexpr int NB = 4;

static constexpr int GB = 64;          // gram K-slices per batch (256 blocks = 1/CU)
static constexpr int GSL = SN / GB;    // 1728
static constexpr int GCH = GSL / 64;   // 27 chunks of K=64

static constexpr int PB = 432;         // pv s-blocks per batch (256 s each)
static constexpr int PCH = 4;          // chunks of 64 s per block

typedef float  f32x4  __attribute__((ext_vector_type(4)));
typedef short  bf16x8 __attribute__((ext_vector_type(8)));
typedef unsigned short u16x8 __attribute__((ext_vector_type(8)));
typedef unsigned short u16x4 __attribute__((ext_vector_type(4)));

// f32 -> (hi bf16, lo bf16) round-to-nearest-even, packed lo<<16|hi
__device__ __forceinline__ unsigned int splitpack(float v) {
    unsigned int u = __float_as_uint(v);
    unsigned int h = (u + 0x7fffu + ((u >> 16) & 1u)) >> 16;
    float lf = v - __uint_as_float(h << 16);
    unsigned int ul = __float_as_uint(lf);
    unsigned int l = (ul + 0x7fffu + ((ul >> 16) & 1u)) >> 16;
    return (l << 16) | (h & 0xffffu);
}
__device__ __forceinline__ unsigned short f2bh(float v) {
    unsigned int u = __float_as_uint(v);
    return (unsigned short)((u + 0x7fffu + ((u >> 16) & 1u)) >> 16);
}

// swizzled LDS fragment read: pitch 128B (gram) / 256B (pv), (row&7)<<4 XOR
__device__ __forceinline__ bf16x8 ldsfrag(const unsigned short* base, int row, int kbyte, int pitchB) {
    const char* p = reinterpret_cast<const char*>(base) + row * pitchB + (kbyte ^ ((row & 7) << 4));
    return *reinterpret_cast<const bf16x8*>(p);
}
__device__ __forceinline__ f32x4 mm(bf16x8 a, bf16x8 b, f32x4 c) {
    return __builtin_amdgcn_mfma_f32_16x16x32_bf16(a, b, c, 0, 0, 0);
}

// ---------------- K1: Gram via MFMA, hi/lo split, 64x64 tiles + K-split ----------------
// grid (GB, NB), block 512 (8 waves). Wave w: tile (wr,wc) = ((w>>1)&1, w&1),
// K-half kh = w>>2. Each block: K-slice of 1728, 27 chunks of K=64.
// LDS: 2 x ([128 c][64 k] bf16 hi + lo), pitch 128B, XOR-swizzled. 64 KB.
// Epilogue: waves 4-7 dump acc into staging LDS, waves 0-3 add (fixed order).
template <bool ATOMIC>
__global__ __launch_bounds__(512, 1) void gram_mfma(const float* __restrict__ x,
                                                    float* __restrict__ dst) {
    __shared__ __align__(16) unsigned short lh[2][CN * 64];   // 16 KB each
    __shared__ __align__(16) unsigned short ll[2][CN * 64];
    const int bx = blockIdx.x, n = blockIdx.y;
    const int tid = threadIdx.x;
    const int lane = tid & 63;
    const int w = tid >> 6;                // 0..7
    const int wr = (w >> 1) & 1, wc = w & 1;   // 2x2 tile grid, tiles 64x64
    const int kh = w >> 2;                 // K-half 0/1
    const int ra = lane & 15, kg = lane >> 4;

    // staging mapping: thread -> (channel c, 16 consecutive k)  [identical R6]
    const int c  = tid >> 2;               // 0..127
    const int ks = (tid & 3) << 4;         // 0,16,32,48
    const float* gq = x + (size_t)n * CN * SN + (size_t)c * SN + bx * GSL;

    f32x4 acc[4][4];
#pragma unroll
    for (int a = 0; a < 4; ++a)
#pragma unroll
        for (int b = 0; b < 4; ++b) acc[a][b] = (f32x4){0.f, 0.f, 0.f, 0.f};

    float4 st[4];
    auto load_chunk = [&](int t) {
        const float4* p = reinterpret_cast<const float4*>(gq + t * 64 + ks);
        st[0] = p[0]; st[1] = p[1]; st[2] = p[2]; st[3] = p[3];
    };

    auto stage = [&](int buf) {
        u16x8 ha, hb, la, lb;
        unsigned int p;
#define CV8(hv, lv, i, val) { p = splitpack(val); hv[i] = (unsigned short)(p & 0xffffu); lv[i] = (unsigned short)(p >> 16); }
        CV8(ha, la, 0, st[0].x) CV8(ha, la, 1, st[0].y) CV8(ha, la, 2, st[0].z) CV8(ha, la, 3, st[0].w)
        CV8(ha, la, 4, st[1].x) CV8(ha, la, 5, st[1].y) CV8(ha, la, 6, st[1].z) CV8(ha, la, 7, st[1].w)
        CV8(hb, lb, 0, st[2].x) CV8(hb, lb, 1, st[2].y) CV8(hb, lb, 2, st[2].z) CV8(hb, lb, 3, st[2].w)
        CV8(hb, lb, 4, st[3].x) CV8(hb, lb, 5, st[3].y) CV8(hb, lb, 6, st[3].z) CV8(hb, lb, 7, st[3].w)
#undef CV8
        char* ph = reinterpret_cast<char*>(lh[buf]) + c * 128;
        char* pl = reinterpret_cast<char*>(ll[buf]) + c * 128;
        const int sw = (c & 7) << 4;
        const int k2 = ks * 2;
        *reinterpret_cast<u16x8*>(ph + (k2 ^ sw))        = ha;
        *reinterpret_cast<u16x8*>(ph + ((k2 + 16) ^ sw)) = hb;
        *reinterpret_cast<u16x8*>(pl + (k2 ^ sw))        = la;
        *reinterpret_cast<u16x8*>(pl + ((k2 + 16) ^ sw)) = lb;
    };

    auto compute = [&](int buf) {
        const unsigned short* LH = lh[buf];
        const unsigned short* LL = ll[buf];
        const int kb = (kh << 6) + (kg << 4);   // this wave's K-half
        bf16x8 ah[4], al[4], bh[4], bl[4];
#pragma unroll
        for (int it = 0; it < 4; ++it) {
            const int row = wr * 64 + it * 16 + ra;
            ah[it] = ldsfrag(LH, row, kb, 128);
            al[it] = ldsfrag(LL, row, kb, 128);
        }
#pragma unroll
        for (int jt = 0; jt < 4; ++jt) {
            const int row = wc * 64 + jt * 16 + ra;
            bh[jt] = ldsfrag(LH, row, kb, 128);
            bl[jt] = ldsfrag(LL, row, kb, 128);
        }
#pragma unroll
        for (int it = 0; it < 4; ++it)
#pragma unroll
            for (int jt = 0; jt < 4; ++jt) {
                acc[it][jt] = mm(ah[it], bh[jt], acc[it][jt]);
                acc[it][jt] = mm(ah[it], bl[jt], acc[it][jt]);
                acc[it][jt] = mm(al[it], bh[jt], acc[it][jt]);
            }
    };

    load_chunk(0);
    for (int t = 0; t < GCH; ++t) {
        stage(t & 1);
        if (t < GCH - 1) load_chunk(t + 1);   // prefetch overlaps MFMA
        __syncthreads();                      // single barrier per chunk (dbuf)
        compute(t & 1);
    }

    // -------- epilogue: cross-K-half reduce via LDS (fixed order), then store --------
    __syncthreads();    // all compute LDS reads done before reuse
    // tile t = w&3 -> exchange region: 0->lh[0], 1->lh[1], 2->ll[0], 3->ll[1]
    float* ex = (w & 2) ? reinterpret_cast<float*>(ll[w & 1])
                        : reinterpret_cast<float*>(lh[w & 1]);
    if (w >= 4) {
#pragma unroll
        for (int it = 0; it < 4; ++it)
#pragma unroll
            for (int jt = 0; jt < 4; ++jt)
                *reinterpret_cast<f32x4*>(ex + (it * 4 + jt) * 256 + lane * 4) = acc[it][jt];
    }
    __syncthreads();
    if (w < 4) {
#pragma unroll
        for (int it = 0; it < 4; ++it)
#pragma unroll
            for (int jt = 0; jt < 4; ++jt)
                acc[it][jt] += *reinterpret_cast<const f32x4*>(ex + (it * 4 + jt) * 256 + lane * 4);

        // C/D map row=(lane>>4)*4+q, col=lane&15
        const int q4 = kg << 2;
        if (!ATOMIC) {
            float* P = dst + (size_t)(n * GB + bx) * (CN * CN);
#pragma unroll
            for (int it = 0; it < 4; ++it)
#pragma unroll
                for (int jt = 0; jt < 4; ++jt)
#pragma unroll
                    for (int q = 0; q < 4; ++q)
                        __builtin_nontemporal_store(acc[it][jt][q],
                            &P[(wr * 64 + it * 16 + q4 + q) * CN + wc * 64 + jt * 16 + ra]);
        } else {
            float* E = dst + (size_t)n * CN * CN;
#pragma unroll
            for (int it = 0; it < 4; ++it)
#pragma unroll
                for (int jt = 0; jt < 4; ++jt)
#pragma unroll
                    for (int q = 0; q < 4; ++q)
                        atomicAdd(&E[(wr * 64 + it * 16 + q4 + q) * CN + wc * 64 + jt * 16 + ra], acc[it][jt][q]);
        }
    }
}

// ---------------- K2: fused reduce + softmin -> bf16-hi attention ----------------
// grid (CN, NB), block 256 (4 waves/row): wave w sums k in [w*16, w*16+16),
// LDS tree combine in fixed k-order (deterministic), wave 0 does softmax.
template <bool REDUCE>
__global__ __launch_bounds__(256) void finish_kernel(const float* __restrict__ src,
                                                     unsigned short* __restrict__ att_h) {
    __shared__ float red[8][64];
    const int i = blockIdx.x, n = blockIdx.y;
    const int tid = threadIdx.x;
    const int lane = tid & 63, w = tid >> 6;
    float e0 = 0.f, e1 = 0.f;
    if (REDUCE) {
        const float* p = src + (size_t)n * GB * (CN * CN) + i * CN;
#pragma unroll
        for (int k = 0; k < GB / 4; ++k) {
            const size_t o = (size_t)(w * (GB / 4) + k) * (CN * CN);
            e0 += __builtin_nontemporal_load(&p[o + lane]);
            e1 += __builtin_nontemporal_load(&p[o + lane + 64]);
        }
        red[w * 2][lane]     = e0;
        red[w * 2 + 1][lane] = e1;
        __syncthreads();
        if (w != 0) return;
        e0 = ((red[0][lane] + red[2][lane]) + (red[4][lane] + red[6][lane]));
        e1 = ((red[1][lane] + red[3][lane]) + (red[5][lane] + red[7][lane]));
    } else {
        if (w != 0) return;
        const float* E = src + ((size_t)n * CN + i) * CN;
        e0 = E[lane]; e1 = E[lane + 64];
    }
    float m = fminf(e0, e1);
#pragma unroll
    for (int off = 32; off > 0; off >>= 1) m = fminf(m, __shfl_xor(m, off));
    const float p0 = expf(m - e0);
    const float p1 = expf(m - e1);
    float s = p0 + p1;
#pragma unroll
    for (int off = 32; off > 0; off >>= 1) s += __shfl_xor(s, off);
    const float inv = 1.f / s;
    const size_t o = ((size_t)n * CN + i) * CN;
    att_h[o + lane]      = f2bh(p0 * inv);
    att_h[o + lane + 64] = f2bh(p1 * inv);
}

// ---------------- K3: out = attn @ Q via MFMA, double-buffered (R6 exact) ----------------
// grid (PB, NB), block 512. Per block: 256 s (4 chunks of 64).
// A = attn-hi in registers. B = q-hi. x loads normal, out stores NT.
// LDS: 2 x [64 s][128 j] bf16 hi, pitch 256B, XOR-swizzled.  32 KB.
__global__ __launch_bounds__(512, 4) void pv_mfma(const float* __restrict__ x,
                                                  const unsigned short* __restrict__ att_h,
                                                  float* __restrict__ out) {
    __shared__ __align__(16) unsigned short qh[2][64 * CN];
    const int bx = blockIdx.x, n = blockIdx.y;
    const int tid = threadIdx.x;
    const int lane = tid & 63;
    const int w = tid >> 6;                 // wave -> i-tile (rows w*16..w*16+15)
    const int ra = lane & 15, kg = lane >> 4;

    // A-fragments from global (attn L2/L3-resident across blocks)
    bf16x8 a_h[4];
    {
        const size_t rowoff = ((size_t)n * CN + w * 16 + ra) * CN + kg * 8;
        const unsigned short* Ah = att_h + rowoff;
#pragma unroll
        for (int kk = 0; kk < 4; ++kk)
            a_h[kk] = *reinterpret_cast<const bf16x8*>(Ah + kk * 32);
    }

    // staging mapping: thread -> 4x4 micro-block (j0..j0+3, s0..s0+3)
    const int j0 = (tid >> 4) * 4;          // 0..124
    const int s0 = (tid & 15) * 4;          // 0..60
    const float* gx = x + (size_t)n * CN * SN;
    const int sbase = bx * (PCH * 64);

    f32x4 st[4];
    auto load_chunk = [&](int sb) {
#pragma unroll
        for (int r = 0; r < 4; ++r)
            st[r] = *reinterpret_cast<const f32x4*>(gx + (size_t)(j0 + r) * SN + sb + s0);
    };

    auto stage = [&](int buf) {
        char* base = reinterpret_cast<char*>(qh[buf]);
#pragma unroll
        for (int r = 0; r < 4; ++r) {       // r = local s offset (compile-time)
            u16x4 hv;
            hv[0] = f2bh(st[0][r]);
            hv[1] = f2bh(st[1][r]);
            hv[2] = f2bh(st[2][r]);
            hv[3] = f2bh(st[3][r]);
            const int s = s0 + r;
            const int off = s * 256 + ((j0 * 2) ^ ((s & 7) << 4));
            *reinterpret_cast<u16x4*>(base + off) = hv;
        }
    };

    auto compute = [&](int buf, int sb) {
        const unsigned short* Q = qh[buf];
#pragma unroll
        for (int stile = 0; stile < 4; ++stile) {
            f32x4 acc = (f32x4){0.f, 0.f, 0.f, 0.f};
            const int srow = stile * 16 + ra;
#pragma unroll
            for (int kk = 0; kk < 4; ++kk) {
                const int kb = kk * 64 + (kg << 4);
                bf16x8 bh = ldsfrag(Q, srow, kb, 256);
                acc = mm(a_h[kk], bh, acc);
            }
            float* o = out + ((size_t)n * CN + w * 16 + (kg << 2)) * SN + sb + stile * 16 + ra;
#pragma unroll
            for (int q = 0; q < 4; ++q)
                __builtin_nontemporal_store(acc[q], o + (size_t)q * SN);
        }
    };

    load_chunk(sbase);
    for (int t = 0; t < PCH; ++t) {
        stage(t & 1);
        if (t < PCH - 1) load_chunk(sbase + (t + 1) * 64);
        __syncthreads();
        compute(t & 1, sbase + t * 64);
    }
}

extern "C" void kernel_launch(void* const* d_in, const int* in_sizes, int n_in,
                              void* d_out, int out_size, void* d_ws, size_t ws_size,
                              hipStream_t stream) {
    (void)in_sizes; (void)n_in; (void)out_size;
    const float* x = (const float*)d_in[0];
    float* out = (float*)d_out;

    // ws: [energy 256KB][att_h 128KB][partials 16.8MB]
    float* energy = (float*)d_ws;
    unsigned short* att_h = (unsigned short*)(energy + (size_t)NB * CN * CN);
    float* part = (float*)(att_h + (size_t)NB * CN * CN);
    const size_t need =
        (size_t)NB * CN * CN * sizeof(float) +
        (size_t)NB * CN * CN * sizeof(unsigned short) +
        (size_t)NB * GB * CN * CN * sizeof(float);

    if (ws_size >= need) {
        gram_mfma<false><<<dim3(GB, NB), 512, 0, stream>>>(x, part);
        finish_kernel<true><<<dim3(CN, NB), 256, 0, stream>>>(part, att_h);
    } else {
        hipMemsetAsync(energy, 0, (size_t)NB * CN * CN * sizeof(float), stream);
        gram_mfma<true><<<dim3(GB, NB), 512, 0, stream>>>(x, energy);
        finish_kernel<false><<<dim3(CN, NB), 256, 0, stream>>>(energy, att_h);
    }
    pv_mfma<<<dim3(PB, NB), 512, 0, stream>>>(x, att_h, out);
}

// Round 13
// 134.148 us; speedup vs baseline: 1.5822x; 1.0336x over previous
//
#include <hip/hip_runtime.h>
#include <math.h>

// cSE channel self-attention, bf16-MFMA hi/lo, double-buffered 3-kernel path.
// x: [N=4][C=128][S=110592] f32.  out: same shape f32.
// energy = Q Q^T; attn_ij = exp(rowmin - e_ij)/sum (== reference softmax(max-e));
// out = attn @ Q.
//
// R13: R12 structure (138.6us) with ONE change: all f32->bf16 staging
// conversions use v_cvt_pk_bf16_f32 (1 inst / 2 elements) instead of manual
// bit-twiddled RTNE (~10 ops/element). Gram was VALU/HBM co-limited
// (~2560cy VALU vs 3196cy HBM per chunk); this drops conversion to ~770cy.

static constexpr int CN = 128;
static constexpr int SN = 110592;      // 48^3
static constexpr int NB = 4;

static constexpr int GB = 64;          // gram K-slices per batch (256 blocks = 1/CU)
static constexpr int GSL = SN / GB;    // 1728
static constexpr int GCH = GSL / 64;   // 27 chunks of K=64

static constexpr int PB = 432;         // pv s-blocks per batch (256 s each)
static constexpr int PCH = 4;          // chunks of 64 s per block

typedef float  f32x4  __attribute__((ext_vector_type(4)));
typedef short  bf16x8 __attribute__((ext_vector_type(8)));
typedef unsigned short u16x4 __attribute__((ext_vector_type(4)));

// packed pair convert: dst[15:0]=bf16(a), dst[31:16]=bf16(b)  (RTNE)
__device__ __forceinline__ unsigned int cvtpk(float a, float b) {
    unsigned int r;
    asm("v_cvt_pk_bf16_f32 %0, %1, %2" : "=v"(r) : "v"(a), "v"(b));
    return r;
}
__device__ __forceinline__ unsigned short f2bh(float v) {
    unsigned int u = __float_as_uint(v);
    return (unsigned short)((u + 0x7fffu + ((u >> 16) & 1u)) >> 16);
}

// swizzled LDS fragment read: pitch 128B (gram) / 256B (pv), (row&7)<<4 XOR
__device__ __forceinline__ bf16x8 ldsfrag(const unsigned short* base, int row, int kbyte, int pitchB) {
    const char* p = reinterpret_cast<const char*>(base) + row * pitchB + (kbyte ^ ((row & 7) << 4));
    return *reinterpret_cast<const bf16x8*>(p);
}
__device__ __forceinline__ f32x4 mm(bf16x8 a, bf16x8 b, f32x4 c) {
    return __builtin_amdgcn_mfma_f32_16x16x32_bf16(a, b, c, 0, 0, 0);
}

// ---------------- K1: Gram via MFMA, hi/lo split, 64x64 tiles + K-split ----------------
// grid (GB, NB), block 512 (8 waves). Wave w: tile (wr,wc) = ((w>>1)&1, w&1),
// K-half kh = w>>2. Each block: K-slice of 1728, 27 chunks of K=64.
// LDS: 2 x ([128 c][64 k] bf16 hi + lo), pitch 128B, XOR-swizzled. 64 KB.
// Epilogue: waves 4-7 dump acc into staging LDS, waves 0-3 add (fixed order).
template <bool ATOMIC>
__global__ __launch_bounds__(512, 1) void gram_mfma(const float* __restrict__ x,
                                                    float* __restrict__ dst) {
    __shared__ __align__(16) unsigned short lh[2][CN * 64];   // 16 KB each
    __shared__ __align__(16) unsigned short ll[2][CN * 64];
    const int bx = blockIdx.x, n = blockIdx.y;
    const int tid = threadIdx.x;
    const int lane = tid & 63;
    const int w = tid >> 6;                // 0..7
    const int wr = (w >> 1) & 1, wc = w & 1;   // 2x2 tile grid, tiles 64x64
    const int kh = w >> 2;                 // K-half 0/1
    const int ra = lane & 15, kg = lane >> 4;

    // staging mapping: thread -> (channel c, 16 consecutive k)
    const int c  = tid >> 2;               // 0..127
    const int ks = (tid & 3) << 4;         // 0,16,32,48
    const float* gq = x + (size_t)n * CN * SN + (size_t)c * SN + bx * GSL;

    f32x4 acc[4][4];
#pragma unroll
    for (int a = 0; a < 4; ++a)
#pragma unroll
        for (int b = 0; b < 4; ++b) acc[a][b] = (f32x4){0.f, 0.f, 0.f, 0.f};

    float4 st[4];
    auto load_chunk = [&](int t) {
        const float4* p = reinterpret_cast<const float4*>(gq + t * 64 + ks);
        st[0] = p[0]; st[1] = p[1]; st[2] = p[2]; st[3] = p[3];
    };

    auto stage = [&](int buf) {
        unsigned int hw[8], lw[8];
#pragma unroll
        for (int r = 0; r < 4; ++r) {
            const unsigned int hp0 = cvtpk(st[r].x, st[r].y);
            const unsigned int hp1 = cvtpk(st[r].z, st[r].w);
            const unsigned int lp0 = cvtpk(st[r].x - __uint_as_float(hp0 << 16),
                                           st[r].y - __uint_as_float(hp0 & 0xffff0000u));
            const unsigned int lp1 = cvtpk(st[r].z - __uint_as_float(hp1 << 16),
                                           st[r].w - __uint_as_float(hp1 & 0xffff0000u));
            hw[r * 2] = hp0; hw[r * 2 + 1] = hp1;
            lw[r * 2] = lp0; lw[r * 2 + 1] = lp1;
        }
        char* ph = reinterpret_cast<char*>(lh[buf]) + c * 128;
        char* pl = reinterpret_cast<char*>(ll[buf]) + c * 128;
        const int sw = (c & 7) << 4;
        const int k2 = ks * 2;
        *reinterpret_cast<uint4*>(ph + (k2 ^ sw))        = make_uint4(hw[0], hw[1], hw[2], hw[3]);
        *reinterpret_cast<uint4*>(ph + ((k2 + 16) ^ sw)) = make_uint4(hw[4], hw[5], hw[6], hw[7]);
        *reinterpret_cast<uint4*>(pl + (k2 ^ sw))        = make_uint4(lw[0], lw[1], lw[2], lw[3]);
        *reinterpret_cast<uint4*>(pl + ((k2 + 16) ^ sw)) = make_uint4(lw[4], lw[5], lw[6], lw[7]);
    };

    auto compute = [&](int buf) {
        const unsigned short* LH = lh[buf];
        const unsigned short* LL = ll[buf];
        const int kb = (kh << 6) + (kg << 4);   // this wave's K-half
        bf16x8 ah[4], al[4], bh[4], bl[4];
#pragma unroll
        for (int it = 0; it < 4; ++it) {
            const int row = wr * 64 + it * 16 + ra;
            ah[it] = ldsfrag(LH, row, kb, 128);
            al[it] = ldsfrag(LL, row, kb, 128);
        }
#pragma unroll
        for (int jt = 0; jt < 4; ++jt) {
            const int row = wc * 64 + jt * 16 + ra;
            bh[jt] = ldsfrag(LH, row, kb, 128);
            bl[jt] = ldsfrag(LL, row, kb, 128);
        }
#pragma unroll
        for (int it = 0; it < 4; ++it)
#pragma unroll
            for (int jt = 0; jt < 4; ++jt) {
                acc[it][jt] = mm(ah[it], bh[jt], acc[it][jt]);
                acc[it][jt] = mm(ah[it], bl[jt], acc[it][jt]);
                acc[it][jt] = mm(al[it], bh[jt], acc[it][jt]);
            }
    };

    load_chunk(0);
    for (int t = 0; t < GCH; ++t) {
        stage(t & 1);
        if (t < GCH - 1) load_chunk(t + 1);   // prefetch overlaps MFMA
        __syncthreads();                      // single barrier per chunk (dbuf)
        compute(t & 1);
    }

    // -------- epilogue: cross-K-half reduce via LDS (fixed order), then store --------
    __syncthreads();    // all compute LDS reads done before reuse
    float* ex = (w & 2) ? reinterpret_cast<float*>(ll[w & 1])
                        : reinterpret_cast<float*>(lh[w & 1]);
    if (w >= 4) {
#pragma unroll
        for (int it = 0; it < 4; ++it)
#pragma unroll
            for (int jt = 0; jt < 4; ++jt)
                *reinterpret_cast<f32x4*>(ex + (it * 4 + jt) * 256 + lane * 4) = acc[it][jt];
    }
    __syncthreads();
    if (w < 4) {
#pragma unroll
        for (int it = 0; it < 4; ++it)
#pragma unroll
            for (int jt = 0; jt < 4; ++jt)
                acc[it][jt] += *reinterpret_cast<const f32x4*>(ex + (it * 4 + jt) * 256 + lane * 4);

        const int q4 = kg << 2;
        if (!ATOMIC) {
            float* P = dst + (size_t)(n * GB + bx) * (CN * CN);
#pragma unroll
            for (int it = 0; it < 4; ++it)
#pragma unroll
                for (int jt = 0; jt < 4; ++jt)
#pragma unroll
                    for (int q = 0; q < 4; ++q)
                        __builtin_nontemporal_store(acc[it][jt][q],
                            &P[(wr * 64 + it * 16 + q4 + q) * CN + wc * 64 + jt * 16 + ra]);
        } else {
            float* E = dst + (size_t)n * CN * CN;
#pragma unroll
            for (int it = 0; it < 4; ++it)
#pragma unroll
                for (int jt = 0; jt < 4; ++jt)
#pragma unroll
                    for (int q = 0; q < 4; ++q)
                        atomicAdd(&E[(wr * 64 + it * 16 + q4 + q) * CN + wc * 64 + jt * 16 + ra], acc[it][jt][q]);
        }
    }
}

// ---------------- K2: fused reduce + softmin -> bf16-hi attention ----------------
// grid (CN, NB), block 256 (4 waves/row): wave w sums k in [w*16, w*16+16),
// LDS tree combine in fixed k-order (deterministic), wave 0 does softmax.
template <bool REDUCE>
__global__ __launch_bounds__(256) void finish_kernel(const float* __restrict__ src,
                                                     unsigned short* __restrict__ att_h) {
    __shared__ float red[8][64];
    const int i = blockIdx.x, n = blockIdx.y;
    const int tid = threadIdx.x;
    const int lane = tid & 63, w = tid >> 6;
    float e0 = 0.f, e1 = 0.f;
    if (REDUCE) {
        const float* p = src + (size_t)n * GB * (CN * CN) + i * CN;
#pragma unroll
        for (int k = 0; k < GB / 4; ++k) {
            const size_t o = (size_t)(w * (GB / 4) + k) * (CN * CN);
            e0 += __builtin_nontemporal_load(&p[o + lane]);
            e1 += __builtin_nontemporal_load(&p[o + lane + 64]);
        }
        red[w * 2][lane]     = e0;
        red[w * 2 + 1][lane] = e1;
        __syncthreads();
        if (w != 0) return;
        e0 = ((red[0][lane] + red[2][lane]) + (red[4][lane] + red[6][lane]));
        e1 = ((red[1][lane] + red[3][lane]) + (red[5][lane] + red[7][lane]));
    } else {
        if (w != 0) return;
        const float* E = src + ((size_t)n * CN + i) * CN;
        e0 = E[lane]; e1 = E[lane + 64];
    }
    float m = fminf(e0, e1);
#pragma unroll
    for (int off = 32; off > 0; off >>= 1) m = fminf(m, __shfl_xor(m, off));
    const float p0 = expf(m - e0);
    const float p1 = expf(m - e1);
    float s = p0 + p1;
#pragma unroll
    for (int off = 32; off > 0; off >>= 1) s += __shfl_xor(s, off);
    const float inv = 1.f / s;
    const size_t o = ((size_t)n * CN + i) * CN;
    att_h[o + lane]      = f2bh(p0 * inv);
    att_h[o + lane + 64] = f2bh(p1 * inv);
}

// ---------------- K3: out = attn @ Q via MFMA, double-buffered ----------------
// grid (PB, NB), block 512. Per block: 256 s (4 chunks of 64).
// A = attn-hi in registers. B = q-hi (cvt_pk staging). x loads normal,
// out stores NT. LDS: 2 x [64 s][128 j] bf16 hi, pitch 256B, XOR-swizzled.
__global__ __launch_bounds__(512, 4) void pv_mfma(const float* __restrict__ x,
                                                  const unsigned short* __restrict__ att_h,
                                                  float* __restrict__ out) {
    __shared__ __align__(16) unsigned short qh[2][64 * CN];
    const int bx = blockIdx.x, n = blockIdx.y;
    const int tid = threadIdx.x;
    const int lane = tid & 63;
    const int w = tid >> 6;                 // wave -> i-tile (rows w*16..w*16+15)
    const int ra = lane & 15, kg = lane >> 4;

    // A-fragments from global (attn L2/L3-resident across blocks)
    bf16x8 a_h[4];
    {
        const size_t rowoff = ((size_t)n * CN + w * 16 + ra) * CN + kg * 8;
        const unsigned short* Ah = att_h + rowoff;
#pragma unroll
        for (int kk = 0; kk < 4; ++kk)
            a_h[kk] = *reinterpret_cast<const bf16x8*>(Ah + kk * 32);
    }

    // staging mapping: thread -> 4x4 micro-block (j0..j0+3, s0..s0+3)
    const int j0 = (tid >> 4) * 4;          // 0..124
    const int s0 = (tid & 15) * 4;          // 0..60
    const float* gx = x + (size_t)n * CN * SN;
    const int sbase = bx * (PCH * 64);

    f32x4 st[4];
    auto load_chunk = [&](int sb) {
#pragma unroll
        for (int r = 0; r < 4; ++r)
            st[r] = *reinterpret_cast<const f32x4*>(gx + (size_t)(j0 + r) * SN + sb + s0);
    };

    auto stage = [&](int buf) {
        char* base = reinterpret_cast<char*>(qh[buf]);
#pragma unroll
        for (int r = 0; r < 4; ++r) {       // r = local s offset (compile-time)
            uint2 hv;
            hv.x = cvtpk(st[0][r], st[1][r]);   // j0+0 (lo), j0+1 (hi)
            hv.y = cvtpk(st[2][r], st[3][r]);   // j0+2, j0+3
            const int s = s0 + r;
            const int off = s * 256 + ((j0 * 2) ^ ((s & 7) << 4));
            *reinterpret_cast<uint2*>(base + off) = hv;
        }
    };

    auto compute = [&](int buf, int sb) {
        const unsigned short* Q = qh[buf];
#pragma unroll
        for (int stile = 0; stile < 4; ++stile) {
            f32x4 acc = (f32x4){0.f, 0.f, 0.f, 0.f};
            const int srow = stile * 16 + ra;
#pragma unroll
            for (int kk = 0; kk < 4; ++kk) {
                const int kb = kk * 64 + (kg << 4);
                bf16x8 bh = ldsfrag(Q, srow, kb, 256);
                acc = mm(a_h[kk], bh, acc);
            }
            float* o = out + ((size_t)n * CN + w * 16 + (kg << 2)) * SN + sb + stile * 16 + ra;
#pragma unroll
            for (int q = 0; q < 4; ++q)
                __builtin_nontemporal_store(acc[q], o + (size_t)q * SN);
        }
    };

    load_chunk(sbase);
    for (int t = 0; t < PCH; ++t) {
        stage(t & 1);
        if (t < PCH - 1) load_chunk(sbase + (t + 1) * 64);
        __syncthreads();
        compute(t & 1, sbase + t * 64);
    }
}

extern "C" void kernel_launch(void* const* d_in, const int* in_sizes, int n_in,
                              void* d_out, int out_size, void* d_ws, size_t ws_size,
                              hipStream_t stream) {
    (void)in_sizes; (void)n_in; (void)out_size;
    const float* x = (const float*)d_in[0];
    float* out = (float*)d_out;

    // ws: [energy 256KB][att_h 128KB][partials 16.8MB]
    float* energy = (float*)d_ws;
    unsigned short* att_h = (unsigned short*)(energy + (size_t)NB * CN * CN);
    float* part = (float*)(att_h + (size_t)NB * CN * CN);
    const size_t need =
        (size_t)NB * CN * CN * sizeof(float) +
        (size_t)NB * CN * CN * sizeof(unsigned short) +
        (size_t)NB * GB * CN * CN * sizeof(float);

    if (ws_size >= need) {
        gram_mfma<false><<<dim3(GB, NB), 512, 0, stream>>>(x, part);
        finish_kernel<true><<<dim3(CN, NB), 256, 0, stream>>>(part, att_h);
    } else {
        hipMemsetAsync(energy, 0, (size_t)NB * CN * CN * sizeof(float), stream);
        gram_mfma<true><<<dim3(GB, NB), 512, 0, stream>>>(x, energy);
        finish_kernel<false><<<dim3(CN, NB), 256, 0, stream>>>(energy, att_h);
    }
    pv_mfma<<<dim3(PB, NB), 512, 0, stream>>>(x, att_h, out);
}